// Round 3
// baseline (1977.669 us; speedup 1.0000x reference)
//
#include <hip/hip_runtime.h>
#include <cstdint>
#include <cstddef>

#define B_DIM 128
#define T_LEN 2048
#define C_DIM 128
#define NSTEP (T_LEN - 1)   // 2047 transition steps / table rows
#define NS4   512           // bp4-path dword-rows

// Skew: F(x) = x + 8*(x>>5). 32-float chunk c sits at 40c.
#define FSKEW(x) ((x) + 8 * ((x) >> 5))

// Barrier WITHOUT vmcnt drain: cross-wave LDS visibility only needs
// lgkmcnt(0). Global loads/stores stay in flight across the barrier.
#define LDS_BARRIER() asm volatile("s_waitcnt lgkmcnt(0)\n\ts_barrier" ::: "memory")

#define TR16_LIST(X) \
    X(0)  X(1)  X(2)  X(3)  X(4)  X(5)  X(6)  X(7)  \
    X(8)  X(9)  X(10) X(11) X(12) X(13) X(14) X(15)

#define TR_LIST(X) \
    X(0)  X(1)  X(2)  X(3)  X(4)  X(5)  X(6)  X(7)  \
    X(8)  X(9)  X(10) X(11) X(12) X(13) X(14) X(15) \
    X(16) X(17) X(18) X(19) X(20) X(21) X(22) X(23) \
    X(24) X(25) X(26) X(27) X(28) X(29) X(30) X(31)

template <int CTRL>
__device__ __forceinline__ float dppf(float x)
{
    return __int_as_float(__builtin_amdgcn_update_dpp(
        0, __float_as_int(x), CTRL, 0xF, 0xF, true));
}

// exact 16-way max, fuses to v_max3 (static indexing only)
__device__ __forceinline__ float max16(const float s[16])
{
    const float u0 = fmaxf(fmaxf(s[0], s[1]), s[2]);
    const float u1 = fmaxf(fmaxf(s[3], s[4]), s[5]);
    const float u2 = fmaxf(fmaxf(s[6], s[7]), s[8]);
    const float u3 = fmaxf(fmaxf(s[9], s[10]), s[11]);
    const float u4 = fmaxf(s[12], s[13]);
    const float u5 = fmaxf(s[14], s[15]);
    return fmaxf(fmaxf(fmaxf(u0, u1), fmaxf(u2, u3)), fmaxf(u4, u5));
}

// ===========================================================================
// Forward, value-only, 2 BATCHES PER BLOCK (1024 thr = 16 waves, 4/SIMD).
// Each 512-thread group g handles batch 2*blockIdx.x+g with its own
// alpha double-buffer; the shared block barrier syncs both (harmless).
// 4 waves/SIMD stagger ds_read latency + compute -> fills the ~500cyc/step
// serial-chain stalls that limited R1 (828 cyc/step @ 2 waves/SIMD).
// Group layout: wave w owns 16 cols; lane: d3 = l&7 -> i in [16d3,16d3+16),
// m = l>>3 -> cols j0 = 16w+m, j1 = j0+8 (J=2: each alpha read feeds 2 cols).
// Reduction over d3: DPP xor1 (0xB1), xor2 (0x4E), half-mirror (0x141).
// ===========================================================================
__global__ __launch_bounds__(1024)
void viterbi_fwd_a(
    const float* __restrict__ pot,
    const float* __restrict__ trans,
    float* __restrict__ alphaG,        // [B][2047][C]: row r = alpha_r
    int* __restrict__ lastTag)
{
    const int g    = threadIdx.x >> 9;         // batch sub-group 0/1
    const int tidl = threadIdx.x & 511;
    const int b    = 2 * blockIdx.x + g;
    const int w    = tidl >> 6;                // 0..7
    const int l    = tidl & 63;
    const int d3   = l & 7;                    // i-chunk [16d3, 16d3+16)
    const int m    = l >> 3;                   // 0..7
    const int j0   = 16 * w + m;
    const int j1   = j0 + 8;
    const int fj0  = FSKEW(j0);
    const int fj1  = FSKEW(j1);
    const int ib   = 16 * d3;

    __shared__ __align__(16) float alphabuf[2][2][160];
    float (*abuf)[160] = alphabuf[g];

#define DECL_TR2(K) \
    const float trA_##K = trans[(ib + (K)) * C_DIM + j0]; \
    const float trB_##K = trans[(ib + (K)) * C_DIM + j1];
    TR16_LIST(DECL_TR2)
#undef DECL_TR2

    const float* potb = pot + (size_t)b * T_LEN * C_DIM;
    float* aG = alphaG + (size_t)b * NSTEP * C_DIM;

    // alpha0 = pot[:,0] into buf[1] (step t=1 reads buf[1]) and aG row 0
    if (tidl < C_DIM) {
        const float a0 = potb[tidl];
        abuf[1][FSKEW(tidl)] = a0;
        aG[tidl] = a0;
    }

    // pot prefetch queues, depth 4 (d3==0 writer lanes)
    float pqA0 = 0.f, pqA1 = 0.f, pqA2 = 0.f, pqA3 = 0.f;
    float pqB0 = 0.f, pqB1 = 0.f, pqB2 = 0.f, pqB3 = 0.f;
    if (d3 == 0) {
        pqA0 = potb[1 * C_DIM + j0];  pqB0 = potb[1 * C_DIM + j1];
        pqA1 = potb[2 * C_DIM + j0];  pqB1 = potb[2 * C_DIM + j1];
        pqA2 = potb[3 * C_DIM + j0];  pqB2 = potb[3 * C_DIM + j1];
        pqA3 = potb[4 * C_DIM + j0];  pqB3 = potb[4 * C_DIM + j1];
    }
    __syncthreads();   // init barrier: full drain once, fine

#define ADD_TRA(K) sA_[K] = a_[K] + trA_##K;
#define ADD_TRB(K) sB_[K] = a_[K] + trB_##K;

    // half-chunk base: d3=2c+h -> LDS float offset 40c+16h (2-way bank
    // alias between chunk pairs -> free per m136)
#define STEP_A(T_, PQA_, PQB_)                                                \
    {                                                                         \
        const float* ac_ =                                                    \
            &abuf[(T_) & 1][40 * (d3 >> 1) + 16 * (d3 & 1)];                  \
        float a_[16];                                                         \
        _Pragma("unroll")                                                     \
        for (int e_ = 0; e_ < 4; ++e_)                                        \
            *(float4*)&a_[4 * e_] = *(const float4*)&ac_[4 * e_];             \
        float sA_[16], sB_[16];                                               \
        TR16_LIST(ADD_TRA)                                                    \
        TR16_LIST(ADD_TRB)                                                    \
        float vA_ = max16(sA_);                                               \
        float vB_ = max16(sB_);                                               \
        vA_ = fmaxf(vA_, dppf<0xB1>(vA_));                                    \
        vB_ = fmaxf(vB_, dppf<0xB1>(vB_));                                    \
        vA_ = fmaxf(vA_, dppf<0x4E>(vA_));                                    \
        vB_ = fmaxf(vB_, dppf<0x4E>(vB_));                                    \
        vA_ = fmaxf(vA_, dppf<0x141>(vA_));                                   \
        vB_ = fmaxf(vB_, dppf<0x141>(vB_));                                   \
        if (d3 == 0) {                                                        \
            const float avA_ = vA_ + (PQA_);                                  \
            const float avB_ = vB_ + (PQB_);                                  \
            abuf[((T_) + 1) & 1][fj0] = avA_;                                 \
            abuf[((T_) + 1) & 1][fj1] = avB_;                                 \
            if ((T_) < T_LEN - 1) {                                           \
                aG[(size_t)(T_) * C_DIM + j0] = avA_;                         \
                aG[(size_t)(T_) * C_DIM + j1] = avB_;                         \
            }                                                                 \
            if ((T_) + 4 < T_LEN) {                                           \
                PQA_ = potb[((T_) + 4) * C_DIM + j0];                         \
                PQB_ = potb[((T_) + 4) * C_DIM + j1];                         \
            }                                                                 \
        }                                                                     \
        LDS_BARRIER();                                                        \
    }

    for (int t = 1; t < 2045; t += 4) {
        STEP_A(t + 0, pqA0, pqB0)
        STEP_A(t + 1, pqA1, pqB1)
        STEP_A(t + 2, pqA2, pqB2)
        STEP_A(t + 3, pqA3, pqB3)
    }
    STEP_A(2045, pqA0, pqB0)
    STEP_A(2046, pqA1, pqB1)
    STEP_A(2047, pqA2, pqB2)
#undef STEP_A
#undef ADD_TRA
#undef ADD_TRB

    // last_tag = first-index argmax of final alpha (in abuf[0]), wave 0 of
    // each group
    if (tidl < 64) {
        const float* af = abuf[0];
        const float v0 = af[FSKEW(tidl)];
        const float v1 = af[FSKEW(tidl + 64)];
        float v = v0; int x = tidl;
        if (v1 > v0) { v = v1; x = tidl + 64; }
#pragma unroll
        for (int mk = 1; mk < 64; mk <<= 1) {
            const float pv = __shfl_xor(v, mk);
            const int   px = __shfl_xor(x, mk);
            if (pv > v || (pv == v && px < x)) { v = pv; x = px; }
        }
        if (tidl == 0) lastTag[b] = x;
    }
}

// ===========================================================================
// Backpointer-table generation: f_t[j] = argmax_i(alpha_{t-1}[i] + T[i][j]),
// first-index on ties (ascending strict-> scan). Fully parallel over (b,t):
// grid (128 t-tiles, 128 b), 256 thr = 2 t-slots x 128 cols. Each thread
// holds its T column in 128 VGPRs (loaded coalesced: row i read by 128
// consecutive lanes); alpha row read as broadcast float4 (L1/L2 hit).
// 4 quarter-chains give ILP-4 on the cmp/csel recurrence; quarter-local
// indices 0..31 stay inline constants; bases added at the 3 merges
// (strictly-greater keeps the lower quarter on ties => global first-index).
// Bit-exact: alphaG holds exact forward alphas; s_i = one fp32 add, same
// as reference.
// ===========================================================================
__global__ __launch_bounds__(256)
__attribute__((amdgpu_waves_per_eu(2)))
void viterbi_bptab(
    const float* __restrict__ alphaG,
    const float* __restrict__ trans,
    unsigned char* __restrict__ tabG)      // [B][2047][C] bytes
{
    const int gtile = blockIdx.x;          // 16-step t-tile
    const int b     = blockIdx.y;
    const int jcol  = threadIdx.x & 127;
    const int ts    = threadIdx.x >> 7;    // t-slot 0/1

    float trr[128];
#pragma unroll
    for (int i = 0; i < 128; ++i)
        trr[i] = trans[i * C_DIM + jcol];

    const float* ab = alphaG + (size_t)b * NSTEP * C_DIM;
    unsigned char* tb = tabG + (size_t)b * NSTEP * C_DIM;

#define QUARTER(Q, VM, IX)                                                    \
    _Pragma("unroll")                                                         \
    for (int k = 0; k < 8; ++k) {                                             \
        const float4 a4 = *(const float4*)(ar + 32 * (Q) + 4 * k);            \
        float s;                                                              \
        s = a4.x + trr[32 * (Q) + 4 * k + 0];                                 \
        if (s > VM) { VM = s; IX = 4 * k + 0; }                               \
        s = a4.y + trr[32 * (Q) + 4 * k + 1];                                 \
        if (s > VM) { VM = s; IX = 4 * k + 1; }                               \
        s = a4.z + trr[32 * (Q) + 4 * k + 2];                                 \
        if (s > VM) { VM = s; IX = 4 * k + 2; }                               \
        s = a4.w + trr[32 * (Q) + 4 * k + 3];                                 \
        if (s > VM) { VM = s; IX = 4 * k + 3; }                               \
    }

#pragma unroll 1
    for (int it = 0; it < 8; ++it) {
        const int t = 16 * gtile + 2 * it + ts;
        if (t < 1 || t > NSTEP) continue;
        const float* ar = ab + (size_t)(t - 1) * C_DIM;

        float vm0 = -3.402823466e38f, vm1 = vm0, vm2 = vm0, vm3 = vm0;
        int ix0 = 0, ix1 = 0, ix2 = 0, ix3 = 0;
        QUARTER(0, vm0, ix0)
        QUARTER(1, vm1, ix1)
        QUARTER(2, vm2, ix2)
        QUARTER(3, vm3, ix3)

        float v01 = vm0; int i01 = ix0;
        if (vm1 > v01) { v01 = vm1; i01 = ix1 + 32; }
        float v23 = vm2; int i23 = ix2;
        if (vm3 > v23) { v23 = vm3; i23 = ix3 + 32; }
        int idx = i01;
        if (v23 > v01) idx = i23 + 64;

        tb[(size_t)(t - 1) * C_DIM + jcol] = (unsigned char)idx;
    }
#undef QUARTER
}

// ===========================================================================
// Chase: tag_{t-1} = tab[t-1][tag_t], staged through LDS in 8 phases of
// 256 rows (32 KB), double-buffered: waves 1-3 stage phase p-1 while wave-0
// lane-0 walks phase p from LDS (ds_read_u8 ~130 cyc/step, vs ~900 cyc
// HBM-miss byte chase). One block per batch.
// ===========================================================================
__global__ __launch_bounds__(256, 1)
void viterbi_chase(
    const unsigned char* __restrict__ tabG,
    const int* __restrict__ lastTag,
    float* __restrict__ out)
{
    const int b   = blockIdx.x;
    const int tid = threadIdx.x;
    __shared__ __align__(16) unsigned char tabS[2][256 * 128];   // 64 KiB

    const unsigned char* tbase = tabG + (size_t)b * NSTEP * C_DIM;
    float* outb = out + (size_t)b * T_LEN;

    auto stage = [&](int p, int buf, int tlo, int nthr) {
        const int rows  = min(256, NSTEP - 256 * p);
        const int bytes = rows * 128;
        const char* src = (const char*)tbase + (size_t)256 * p * 128;
        for (int ofs = (tid - tlo) * 16; ofs < bytes; ofs += nthr * 16)
            *(uint4*)&tabS[buf][ofs] = *(const uint4*)(src + ofs);
    };

    stage(7, 1, 0, 256);          // prologue: all threads stage phase 7
    int cur = 0;
    if (tid == 0) {
        cur = lastTag[b];
        outb[T_LEN - 1] = (float)cur;
    }
    __syncthreads();

    for (int p = 7; p >= 0; --p) {
        if (tid >= 64 && p > 0) stage(p - 1, (p - 1) & 1, 64, 192);
        if (tid == 0) {
            const int rlo  = 256 * p;
            const int rend = min(rlo + 256, NSTEP) - 1;
            const unsigned char* tp = tabS[p & 1];
            int rofs = (rend - rlo) * 128;
            for (int r = rend; r >= rlo; --r) {
                cur = tp[rofs + cur];
                outb[r] = (float)cur;
                rofs -= 128;
            }
        }
        __syncthreads();
    }
}

// ===========================================================================
// MID FALLBACK bwd (R1-verified): serial recompute-argmax backtrack.
// ===========================================================================
__global__ __launch_bounds__(64, 1) void viterbi_bwd_a(
    const float* __restrict__ alphaG,
    const float* __restrict__ trans,
    const int* __restrict__ lastTag,
    float* __restrict__ out)
{
    const int b = blockIdx.x;
    const int l = threadIdx.x;
    float* outb = out + (size_t)b * T_LEN;

    __shared__ float Tl[C_DIM][C_DIM];   // 64 KiB, swizzled
    for (int k = l; k < C_DIM * C_DIM; k += 64) {
        const int i = k >> 7;
        const int jj = k & 127;
        Tl[i][jj ^ (i & 31)] = trans[k];
    }

    const float* ab = alphaG + (size_t)b * NSTEP * C_DIM;

    float qa0 = 0.f, qb0 = 0.f, qa1 = 0.f, qb1 = 0.f, qa2 = 0.f, qb2 = 0.f,
          qa3 = 0.f, qb3 = 0.f, qa4 = 0.f, qb4 = 0.f, qa5 = 0.f, qb5 = 0.f;
    auto ld = [&](int r, float& A, float& Bv) {
        if (r >= 0) {
            const float* p = ab + (size_t)r * C_DIM;
            A  = p[l];
            Bv = p[l + 64];
        }
    };
    ld(2046, qa0, qb0);
    ld(2045, qa1, qb1);
    ld(2044, qa2, qb2);
    ld(2043, qa3, qb3);
    ld(2042, qa4, qb4);
    ld(2041, qa5, qb5);

    int cur = lastTag[b];
    if (l == 0) outb[T_LEN - 1] = (float)cur;
    __syncthreads();

    for (int t = T_LEN - 1; t >= 1; --t) {
        const float a0 = qa0, a1 = qb0;
        const int sw = cur ^ (l & 31);
        const float c0 = Tl[l][sw];
        const float c1 = Tl[l + 64][sw];
        const float s0 = a0 + c0;
        const float s1 = a1 + c1;
        float v = fmaxf(s0, s1);
        v = fmaxf(v, dppf<0xB1>(v));
        v = fmaxf(v, dppf<0x4E>(v));
        v = fmaxf(v, dppf<0x141>(v));
        v = fmaxf(v, dppf<0x140>(v));
        v = fmaxf(v, __int_as_float(__builtin_amdgcn_ds_swizzle(
                         __float_as_int(v), 0x401F)));
        v = fmaxf(v, __shfl_xor(v, 32));
        const unsigned long long m0 = __ballot(s0 == v);
        const unsigned long long m1 = __ballot(s1 == v);
        cur = m0 ? (__ffsll(m0) - 1) : (64 + __ffsll(m1) - 1);
        if (l == 0) outb[t - 1] = (float)cur;
        qa0 = qa1; qb0 = qb1; qa1 = qa2; qb1 = qb2;
        qa2 = qa3; qb2 = qb3; qa3 = qa4; qb3 = qb4;
        qa4 = qa5; qb4 = qb5;
        ld(t - 7, qa5, qb5);
    }
}

// ===========================================================================
// FULL FALLBACK (bp4, 32 MiB workspace): verbatim verified kernels.
// ===========================================================================
__global__ __launch_bounds__(512)
__attribute__((amdgpu_waves_per_eu(2, 2)))
void viterbi_fwd(
    const float* __restrict__ pot,
    const float* __restrict__ trans,
    unsigned* __restrict__ bp4,
    int* __restrict__ lastTag)
{
    const int b   = blockIdx.x;
    const int tid = threadIdx.x;
    const int w   = tid >> 6;
    const int l   = tid & 63;
    const int d   = l & 3;
    const int j   = 16 * w + (l >> 2);
    const int fj  = FSKEW(j);
    const int ib  = 32 * d;

    __shared__ __align__(16) float alphabuf[2][160];

#define DECL_TR(K) float tr_##K = trans[(ib + (K)) * C_DIM + j];
    TR_LIST(DECL_TR)
#undef DECL_TR

    const float* potb = pot + (size_t)b * T_LEN * C_DIM;

    if (tid < C_DIM) alphabuf[1][FSKEW(tid)] = potb[tid];

    float pq0 = 0.f, pq1 = 0.f, pq2 = 0.f, pq3 = 0.f;
    if (d == 0) {
        pq0 = potb[1 * C_DIM + j];
        pq1 = potb[2 * C_DIM + j];
        pq2 = potb[3 * C_DIM + j];
        pq3 = potb[4 * C_DIM + j];
    }
    unsigned pack = 0;
    __syncthreads();

#define ADD_TR(K) s_[K] = a_[K] + tr_##K;

#define STEP(T_, C_, PQ_)                                                     \
    {                                                                         \
        const float* ac_ = &alphabuf[(T_) & 1][40 * d];                       \
        float a_[32];                                                         \
        _Pragma("unroll")                                                     \
        for (int e_ = 0; e_ < 8; ++e_)                                        \
            *(float4*)&a_[4 * e_] = *(const float4*)&ac_[4 * e_];             \
        float s_[32];                                                         \
        TR_LIST(ADD_TR)                                                      \
        float v16_[16]; int x16_[16];                                         \
        _Pragma("unroll")                                                     \
        for (int p_ = 0; p_ < 16; ++p_) {                                     \
            const bool g_ = s_[2 * p_ + 1] > s_[2 * p_];                      \
            v16_[p_] = g_ ? s_[2 * p_ + 1] : s_[2 * p_];                      \
            x16_[p_] = g_ ? 2 * p_ + 1 : 2 * p_;                              \
        }                                                                     \
        float v8_[8]; int x8_[8];                                             \
        _Pragma("unroll")                                                     \
        for (int p_ = 0; p_ < 8; ++p_) {                                      \
            const bool g_ = v16_[2 * p_ + 1] > v16_[2 * p_];                  \
            v8_[p_] = g_ ? v16_[2 * p_ + 1] : v16_[2 * p_];                   \
            x8_[p_] = g_ ? x16_[2 * p_ + 1] : x16_[2 * p_];                   \
        }                                                                     \
        float v4_[4]; int x4_[4];                                             \
        _Pragma("unroll")                                                     \
        for (int p_ = 0; p_ < 4; ++p_) {                                      \
            const bool g_ = v8_[2 * p_ + 1] > v8_[2 * p_];                    \
            v4_[p_] = g_ ? v8_[2 * p_ + 1] : v8_[2 * p_];                     \
            x4_[p_] = g_ ? x8_[2 * p_ + 1] : x8_[2 * p_];                     \
        }                                                                     \
        float v2_[2]; int x2_[2];                                             \
        _Pragma("unroll")                                                     \
        for (int p_ = 0; p_ < 2; ++p_) {                                      \
            const bool g_ = v4_[2 * p_ + 1] > v4_[2 * p_];                    \
            v2_[p_] = g_ ? v4_[2 * p_ + 1] : v4_[2 * p_];                     \
            x2_[p_] = g_ ? x4_[2 * p_ + 1] : x4_[2 * p_];                     \
        }                                                                     \
        const bool gf_ = v2_[1] > v2_[0];                                     \
        float v_ = gf_ ? v2_[1] : v2_[0];                                     \
        int   x_ = ib + (gf_ ? x2_[1] : x2_[0]);                              \
        {                                                                     \
            const float pv_ = __int_as_float(__builtin_amdgcn_update_dpp(     \
                0, __float_as_int(v_), 0xB1, 0xF, 0xF, true));                \
            const int   px_ = __builtin_amdgcn_update_dpp(                    \
                0, x_, 0xB1, 0xF, 0xF, true);                                 \
            const bool  pl_ = d & 1;                                          \
            const bool  tk_ = (pv_ > v_) || (pl_ && (pv_ == v_));             \
            if (tk_) { v_ = pv_; x_ = px_; }                                  \
        }                                                                     \
        {                                                                     \
            const float pv_ = __int_as_float(__builtin_amdgcn_update_dpp(     \
                0, __float_as_int(v_), 0x4E, 0xF, 0xF, true));                \
            const int   px_ = __builtin_amdgcn_update_dpp(                    \
                0, x_, 0x4E, 0xF, 0xF, true);                                 \
            const bool  pl_ = (d >> 1) & 1;                                   \
            const bool  tk_ = (pv_ > v_) || (pl_ && (pv_ == v_));             \
            if (tk_) { v_ = pv_; x_ = px_; }                                  \
        }                                                                     \
        if (d == 0) {                                                         \
            alphabuf[((T_) + 1) & 1][fj] = v_ + (PQ_);                        \
            pack |= (unsigned)x_ << (8 * (C_));                               \
            if ((C_) == 3) {                                                  \
                bp4[((size_t)(((T_) - 1) >> 2) * B_DIM + b) * C_DIM + j] =    \
                    pack;                                                     \
                pack = 0;                                                     \
            }                                                                 \
            if ((T_) + 4 < T_LEN) PQ_ = potb[((T_) + 4) * C_DIM + j];         \
        }                                                                     \
        LDS_BARRIER();                                                        \
    }

    for (int t = 1; t < 2045; t += 4) {
        STEP(t + 0, 0, pq0)
        STEP(t + 1, 1, pq1)
        STEP(t + 2, 2, pq2)
        STEP(t + 3, 3, pq3)
    }
    STEP(2045, 0, pq0)
    STEP(2046, 1, pq1)
    STEP(2047, 2, pq2)
    if (d == 0)
        bp4[((size_t)511 * B_DIM + b) * C_DIM + j] = pack;
#undef STEP
#undef ADD_TR

    if (tid < 64) {
        const float* af = alphabuf[0];
        const float v0 = af[FSKEW(tid)];
        const float v1 = af[FSKEW(tid + 64)];
        float v = v0; int x = tid;
        if (v1 > v0) { v = v1; x = tid + 64; }
#pragma unroll
        for (int mk = 1; mk < 64; mk <<= 1) {
            const float pv = __shfl_xor(v, mk);
            const int   px = __shfl_xor(x, mk);
            if (pv > v || (pv == v && px < x)) { v = pv; x = px; }
        }
        if (tid == 0) lastTag[b] = x;
    }
}

__global__ __launch_bounds__(64, 1) void viterbi_bwd(
    const unsigned* __restrict__ bp4,
    const int* __restrict__ lastTag,
    float* __restrict__ out)
{
    const int b = blockIdx.x;
    const int l = threadIdx.x;
    float* outb = out + (size_t)b * T_LEN;

    unsigned qa0 = 0, qb0 = 0, qa1 = 0, qb1 = 0,
             qa2 = 0, qb2 = 0, qa3 = 0, qb3 = 0;

    auto ld = [&](int s4, unsigned& A, unsigned& B) {
        if (s4 >= 0) {
            const unsigned* r = bp4 + ((size_t)s4 * B_DIM + b) * C_DIM;
            A = r[l];
            B = r[l + 64];
        }
    };
    ld(511, qa0, qb0);
    ld(510, qa1, qb1);
    ld(509, qa2, qb2);
    ld(508, qa3, qb3);

    int cur = lastTag[b];

    auto ext = [&](unsigned rA, unsigned rB, int c, int byte) -> int {
        const int addr = (c & 63) << 2;
        const int vA = __builtin_amdgcn_ds_bpermute(addr, (int)rA);
        const int vB = __builtin_amdgcn_ds_bpermute(addr, (int)rB);
        const int v = (c & 64) ? vB : vA;
        return (v >> (byte * 8)) & 0xFF;
    };

    {
        const unsigned rA = qa0, rB = qb0;
        const float t3 = (float)cur;
        cur = ext(rA, rB, cur, 2); const float t2 = (float)cur;
        cur = ext(rA, rB, cur, 1); const float t1 = (float)cur;
        cur = ext(rA, rB, cur, 0); const float t0 = (float)cur;
        if (l == 0) *(float4*)(outb + 4 * 511) = make_float4(t0, t1, t2, t3);
        qa0 = qa1; qb0 = qb1; qa1 = qa2; qb1 = qb2; qa2 = qa3; qb2 = qb3;
        ld(507, qa3, qb3);
    }

    for (int s4 = 510; s4 >= 0; --s4) {
        const unsigned rA = qa0, rB = qb0;
        cur = ext(rA, rB, cur, 3); const float t3 = (float)cur;
        cur = ext(rA, rB, cur, 2); const float t2 = (float)cur;
        cur = ext(rA, rB, cur, 1); const float t1 = (float)cur;
        cur = ext(rA, rB, cur, 0); const float t0 = (float)cur;
        if (l == 0) *(float4*)(outb + 4 * s4) = make_float4(t0, t1, t2, t3);
        qa0 = qa1; qb0 = qb1; qa1 = qa2; qb1 = qb2; qa2 = qa3; qb2 = qb3;
        ld(s4 - 4, qa3, qb3);
    }
}

extern "C" void kernel_launch(void* const* d_in, const int* in_sizes, int n_in,
                              void* d_out, int out_size, void* d_ws, size_t ws_size,
                              hipStream_t stream)
{
    const float* pot   = (const float*)d_in[0];   // [128, 2048, 128] f32
    const float* trans = (const float*)d_in[1];   // [128, 128] f32
    float* out = (float*)d_out;                   // [128, 2048] f32 (tags)

    const size_t alphaBytes = (size_t)B_DIM * NSTEP * C_DIM * sizeof(float); // 134,152,192
    const size_t tabBytes   = (size_t)B_DIM * NSTEP * C_DIM;                 //  33,538,048

    if (ws_size >= alphaBytes + tabBytes + 512) {
        // FULL PATH: value-only fwd -> parallel bp-table gen -> LDS chase
        float* alphaG        = (float*)d_ws;
        unsigned char* tabG  = (unsigned char*)d_ws + alphaBytes;
        int* lastTag         = (int*)((char*)d_ws + alphaBytes + tabBytes);
        viterbi_fwd_a<<<B_DIM / 2, 1024, 0, stream>>>(pot, trans, alphaG, lastTag);
        dim3 gridT(128, B_DIM);
        viterbi_bptab<<<gridT, 256, 0, stream>>>(alphaG, trans, tabG);
        viterbi_chase<<<B_DIM, 256, 0, stream>>>(tabG, lastTag, out);
    } else if (ws_size >= alphaBytes + 512) {
        // MID: value-only fwd + serial recompute backtrack (R1-verified)
        float* alphaG = (float*)d_ws;
        int* lastTag  = (int*)((char*)d_ws + alphaBytes);
        viterbi_fwd_a<<<B_DIM / 2, 1024, 0, stream>>>(pot, trans, alphaG, lastTag);
        viterbi_bwd_a<<<B_DIM, 64, 0, stream>>>(alphaG, trans, lastTag, out);
    } else {
        // FALLBACK: bp4 path (32 MiB workspace)
        unsigned* bp4 = (unsigned*)d_ws;
        int* lastTag  = (int*)((char*)d_ws + (size_t)NS4 * B_DIM * C_DIM * 4);
        viterbi_fwd<<<B_DIM, 512, 0, stream>>>(pot, trans, bp4, lastTag);
        viterbi_bwd<<<B_DIM, 64, 0, stream>>>(bp4, lastTag, out);
    }
}

// Round 4
// 1625.113 us; speedup vs baseline: 1.2169x; 1.2169x over previous
//
#include <hip/hip_runtime.h>
#include <cstdint>
#include <cstddef>

#define B_DIM 128
#define T_LEN 2048
#define C_DIM 128
#define NSTEP (T_LEN - 1)   // 2047 transition steps
#define NS4   512           // bp4-path dword-rows

// Skew: F(x) = x + 8*(x>>5). 32-float chunk c sits at 40c; the 4 chunks'
// ds_read_b128 streams hit disjoint bank quartets (verified conflict-free:
// R1 SQ_LDS_BANK_CONFLICT == 0).
#define FSKEW(x) ((x) + 8 * ((x) >> 5))

// Barrier WITHOUT vmcnt drain: cross-wave LDS visibility only needs
// lgkmcnt(0). Global loads/stores stay in flight across the barrier.
#define LDS_BARRIER() asm volatile("s_waitcnt lgkmcnt(0)\n\ts_barrier" ::: "memory")

#define TR_LIST(X) \
    X(0)  X(1)  X(2)  X(3)  X(4)  X(5)  X(6)  X(7)  \
    X(8)  X(9)  X(10) X(11) X(12) X(13) X(14) X(15) \
    X(16) X(17) X(18) X(19) X(20) X(21) X(22) X(23) \
    X(24) X(25) X(26) X(27) X(28) X(29) X(30) X(31)

template <int CTRL>
__device__ __forceinline__ float dppf(float x)
{
    return __int_as_float(__builtin_amdgcn_update_dpp(
        0, __float_as_int(x), CTRL, 0xF, 0xF, true));
}

// exact 32-way max, fuses to v_max3 chains (static indexing only)
__device__ __forceinline__ float max32(const float s[32])
{
    float u[11];
#pragma unroll
    for (int p = 0; p < 10; ++p)
        u[p] = fmaxf(fmaxf(s[3 * p], s[3 * p + 1]), s[3 * p + 2]);
    u[10] = fmaxf(s[30], s[31]);
    const float w0 = fmaxf(fmaxf(u[0], u[1]), u[2]);
    const float w1 = fmaxf(fmaxf(u[3], u[4]), u[5]);
    const float w2 = fmaxf(fmaxf(u[6], u[7]), u[8]);
    const float w3 = fmaxf(u[9], u[10]);
    return fmaxf(fmaxf(w0, w1), fmaxf(w2, w3));
}

// ===========================================================================
// Forward, value-only (R1-verified structure: 706 us, 0 bank conflicts).
// One block per batch, 512 threads = 8 waves (2/SIMD). Wave w owns j in
// [16w,16w+16); lane l: j = 16w + (l>>2), d = l&3, i in [32d,32d+32).
// Per step: 8 ds_read_b128 + 32 adds + max3 tree + 2 DPP quad merges;
// d==0 lanes write alpha to LDS and V* = max (PRE-pot) to global row T_-1.
// V* is all the backtrack needs: argmax is recovered by equality-matching
// against V* (reduction-free bwd). ONE lgkm-only barrier/step.
// ===========================================================================
__global__ __launch_bounds__(512)
__attribute__((amdgpu_waves_per_eu(2, 2)))
void viterbi_fwd_a(
    const float* __restrict__ pot,
    const float* __restrict__ trans,
    float* __restrict__ vstarG,        // [B][2047][C]: row t-1 = vstar_t
    int* __restrict__ lastTag)
{
    const int b   = blockIdx.x;
    const int tid = threadIdx.x;
    const int w   = tid >> 6;
    const int l   = tid & 63;
    const int d   = l & 3;             // i-chunk: [32d, 32d+32)
    const int j   = 16 * w + (l >> 2);
    const int fj  = FSKEW(j);
    const int ib  = 32 * d;

    __shared__ __align__(16) float alphabuf[2][160];

#define DECL_TR(K) const float tr_##K = trans[(ib + (K)) * C_DIM + j];
    TR_LIST(DECL_TR)
#undef DECL_TR

    const float* potb = pot + (size_t)b * T_LEN * C_DIM;
    float* vG = vstarG + (size_t)b * NSTEP * C_DIM;

    // alpha0 = pot[:,0] into buf[1] (step t=1 reads buf[t&1]=buf[1])
    if (tid < C_DIM) alphabuf[1][FSKEW(tid)] = potb[tid];

    // pot prefetch queue, depth 4 (d==0 lanes only consume it)
    float pq0 = 0.f, pq1 = 0.f, pq2 = 0.f, pq3 = 0.f;
    if (d == 0) {
        pq0 = potb[1 * C_DIM + j];
        pq1 = potb[2 * C_DIM + j];
        pq2 = potb[3 * C_DIM + j];
        pq3 = potb[4 * C_DIM + j];
    }
    __syncthreads();   // init barrier: full drain once, fine

#define ADD_TR(K) s_[K] = a_[K] + tr_##K;

#define STEP_A(T_, PQ_)                                                       \
    {                                                                         \
        const float* ac_ = &alphabuf[(T_) & 1][40 * d];                       \
        float a_[32];                                                         \
        _Pragma("unroll")                                                     \
        for (int e_ = 0; e_ < 8; ++e_)                                        \
            *(float4*)&a_[4 * e_] = *(const float4*)&ac_[4 * e_];             \
        float s_[32];                                                         \
        TR_LIST(ADD_TR)                                                       \
        float v_ = max32(s_);                                                 \
        v_ = fmaxf(v_, dppf<0xB1>(v_));                                       \
        v_ = fmaxf(v_, dppf<0x4E>(v_));                                       \
        if (d == 0) {                                                         \
            alphabuf[((T_) + 1) & 1][fj] = v_ + (PQ_);                        \
            vG[(size_t)((T_) - 1) * C_DIM + j] = v_;                          \
            if ((T_) + 4 < T_LEN) PQ_ = potb[((T_) + 4) * C_DIM + j];         \
        }                                                                     \
        LDS_BARRIER();                                                        \
    }

    // main loop: t = 1 .. 2044 (groups of 4 for the pot-queue rotation)
    for (int t = 1; t < 2045; t += 4) {
        STEP_A(t + 0, pq0)
        STEP_A(t + 1, pq1)
        STEP_A(t + 2, pq2)
        STEP_A(t + 3, pq3)
    }
    // tail: t = 2045, 2046, 2047
    STEP_A(2045, pq0)
    STEP_A(2046, pq1)
    STEP_A(2047, pq2)
#undef STEP_A
#undef ADD_TR

    // last_tag = first-index argmax of final alpha (in buf[0]), wave 0
    if (tid < 64) {
        const float* af = alphabuf[0];
        const float v0 = af[FSKEW(tid)];
        const float v1 = af[FSKEW(tid + 64)];
        float v = v0; int x = tid;
        if (v1 > v0) { v = v1; x = tid + 64; }
#pragma unroll
        for (int mk = 1; mk < 64; mk <<= 1) {
            const float pv = __shfl_xor(v, mk);
            const int   px = __shfl_xor(x, mk);
            if (pv > v || (pv == v && px < x)) { v = pv; x = px; }
        }
        if (tid == 0) lastTag[b] = x;
    }
}

// ===========================================================================
// Reduction-free backtrack. One wave per batch.
// At step t (r = t-1): smax = vstar_t[cur] via register readlane (rows
// prefetched, cur is uniform) -- NO cross-lane max, NO DPP/swizzle hops.
// alpha_{t-1}[i] = vstar_{t-1}[i] + pot_{t-1}[i] (bit-exact replay of
// fwd's av_ = v_ + pq; for t-1==0, vstar term is 0 so alpha_0 = pot_0).
// tag_{t-1} = first i with alpha_{t-1}[i] + T[i][cur] == smax
//           = ballot + ffs (first-index tie-break == jnp.argmax).
// Chain/step: cur -> {readlane || swizzled T-gather(~120cy)} -> add ->
// cmp -> ballot/ffs  (~170 cy vs 908 for the reduce-based bwd).
// ===========================================================================
__global__ __launch_bounds__(64, 1) void viterbi_bwd_v(
    const float* __restrict__ pot,
    const float* __restrict__ vstarG,
    const float* __restrict__ trans,
    const int* __restrict__ lastTag,
    float* __restrict__ out)
{
    const int b = blockIdx.x;
    const int l = threadIdx.x;
    float* outb = out + (size_t)b * T_LEN;
    const float* potb = pot + (size_t)b * T_LEN * C_DIM;
    const float* vbse = vstarG + (size_t)b * NSTEP * C_DIM;

    __shared__ float Tl[C_DIM][C_DIM];   // 64 KiB, swizzled (R1-verified)
    for (int k = l; k < C_DIM * C_DIM; k += 64) {
        const int i = k >> 7;
        const int jj = k & 127;
        Tl[i][jj ^ (i & 31)] = trans[k];
    }

    // queues over row index r, walking 2046 -> 0 (depth 6):
    // p*: pot row r ; v*: vstarG row r (= vstar_{r+1})
    float pa0, pb0, pa1, pb1, pa2, pb2, pa3, pb3, pa4, pb4, pa5, pb5;
    float va0, vb0, va1, vb1, va2, vb2, va3, vb3, va4, vb4, va5, vb5;
    auto ld = [&](int r, float& pa, float& pb, float& va, float& vb) {
        if (r >= 0) {
            pa = potb[(size_t)r * C_DIM + l];
            pb = potb[(size_t)r * C_DIM + l + 64];
            va = vbse[(size_t)r * C_DIM + l];
            vb = vbse[(size_t)r * C_DIM + l + 64];
        } else {
            va = 0.f; vb = 0.f;   // row -1: alpha_0 = pot_0 + 0
        }
    };
    ld(2046, pa0, pb0, va0, vb0);
    ld(2045, pa1, pb1, va1, vb1);
    ld(2044, pa2, pb2, va2, vb2);
    ld(2043, pa3, pb3, va3, vb3);
    ld(2042, pa4, pb4, va4, vb4);
    ld(2041, pa5, pb5, va5, vb5);

    int cur = lastTag[b];
    if (l == 0) outb[T_LEN - 1] = (float)cur;
    __syncthreads();   // Tl visibility

    for (int r = NSTEP - 1; r >= 0; --r) {     // r = t-1
        // smax = vstar_{r+1}[cur]  (row r, already in registers)
        const int cl = cur & 63;
        const float rl0 = __int_as_float(
            __builtin_amdgcn_readlane(__float_as_int(va0), cl));
        const float rl1 = __int_as_float(
            __builtin_amdgcn_readlane(__float_as_int(vb0), cl));
        const float smax = (cur & 64) ? rl1 : rl0;
        // alpha_r (exact replay): pot_r + vstar_r (row r-1 = entry 1)
        const float a0 = pa0 + va1;
        const float a1 = pb0 + vb1;
        // T[:,cur] gather (conflict-free swizzle)
        const int sw = cur ^ (l & 31);
        const float c0 = Tl[l][sw];
        const float c1 = Tl[l + 64][sw];
        const float s0 = a0 + c0;
        const float s1 = a1 + c1;
        // exact first-index argmax: lowest i with s_i == smax
        const unsigned long long m0 = __ballot(s0 == smax);
        const unsigned long long m1 = __ballot(s1 == smax);
        cur = m0 ? (__ffsll(m0) - 1) : (64 + __ffsll(m1) - 1);
        if (l == 0) outb[r] = (float)cur;
        // rotate queues, prefetch row r-6
        pa0 = pa1; pb0 = pb1; va0 = va1; vb0 = vb1;
        pa1 = pa2; pb1 = pb2; va1 = va2; vb1 = vb2;
        pa2 = pa3; pb2 = pb3; va2 = va3; vb2 = vb3;
        pa3 = pa4; pb3 = pb4; va3 = va4; vb3 = vb4;
        pa4 = pa5; pb4 = pb5; va4 = va5; vb4 = vb5;
        ld(r - 6, pa5, pb5, va5, vb5);
    }
}

// ===========================================================================
// FULL FALLBACK (bp4, 32 MiB workspace): verbatim verified kernels.
// ===========================================================================
__global__ __launch_bounds__(512)
__attribute__((amdgpu_waves_per_eu(2, 2)))
void viterbi_fwd(
    const float* __restrict__ pot,
    const float* __restrict__ trans,
    unsigned* __restrict__ bp4,
    int* __restrict__ lastTag)
{
    const int b   = blockIdx.x;
    const int tid = threadIdx.x;
    const int w   = tid >> 6;
    const int l   = tid & 63;
    const int d   = l & 3;
    const int j   = 16 * w + (l >> 2);
    const int fj  = FSKEW(j);
    const int ib  = 32 * d;

    __shared__ __align__(16) float alphabuf[2][160];

#define DECL_TR(K) float tr_##K = trans[(ib + (K)) * C_DIM + j];
    TR_LIST(DECL_TR)
#undef DECL_TR

    const float* potb = pot + (size_t)b * T_LEN * C_DIM;

    if (tid < C_DIM) alphabuf[1][FSKEW(tid)] = potb[tid];

    float pq0 = 0.f, pq1 = 0.f, pq2 = 0.f, pq3 = 0.f;
    if (d == 0) {
        pq0 = potb[1 * C_DIM + j];
        pq1 = potb[2 * C_DIM + j];
        pq2 = potb[3 * C_DIM + j];
        pq3 = potb[4 * C_DIM + j];
    }
    unsigned pack = 0;
    __syncthreads();

#define ADD_TR(K) s_[K] = a_[K] + tr_##K;

#define STEP(T_, C_, PQ_)                                                     \
    {                                                                         \
        const float* ac_ = &alphabuf[(T_) & 1][40 * d];                       \
        float a_[32];                                                         \
        _Pragma("unroll")                                                     \
        for (int e_ = 0; e_ < 8; ++e_)                                        \
            *(float4*)&a_[4 * e_] = *(const float4*)&ac_[4 * e_];             \
        float s_[32];                                                         \
        TR_LIST(ADD_TR)                                                       \
        float v16_[16]; int x16_[16];                                         \
        _Pragma("unroll")                                                     \
        for (int p_ = 0; p_ < 16; ++p_) {                                     \
            const bool g_ = s_[2 * p_ + 1] > s_[2 * p_];                      \
            v16_[p_] = g_ ? s_[2 * p_ + 1] : s_[2 * p_];                      \
            x16_[p_] = g_ ? 2 * p_ + 1 : 2 * p_;                              \
        }                                                                     \
        float v8_[8]; int x8_[8];                                             \
        _Pragma("unroll")                                                     \
        for (int p_ = 0; p_ < 8; ++p_) {                                      \
            const bool g_ = v16_[2 * p_ + 1] > v16_[2 * p_];                  \
            v8_[p_] = g_ ? v16_[2 * p_ + 1] : v16_[2 * p_];                   \
            x8_[p_] = g_ ? x16_[2 * p_ + 1] : x16_[2 * p_];                   \
        }                                                                     \
        float v4_[4]; int x4_[4];                                             \
        _Pragma("unroll")                                                     \
        for (int p_ = 0; p_ < 4; ++p_) {                                      \
            const bool g_ = v8_[2 * p_ + 1] > v8_[2 * p_];                    \
            v4_[p_] = g_ ? v8_[2 * p_ + 1] : v8_[2 * p_];                     \
            x4_[p_] = g_ ? x8_[2 * p_ + 1] : x8_[2 * p_];                     \
        }                                                                     \
        float v2_[2]; int x2_[2];                                             \
        _Pragma("unroll")                                                     \
        for (int p_ = 0; p_ < 2; ++p_) {                                      \
            const bool g_ = v4_[2 * p_ + 1] > v4_[2 * p_];                    \
            v2_[p_] = g_ ? v4_[2 * p_ + 1] : v4_[2 * p_];                     \
            x2_[p_] = g_ ? x4_[2 * p_ + 1] : x4_[2 * p_];                     \
        }                                                                     \
        const bool gf_ = v2_[1] > v2_[0];                                     \
        float v_ = gf_ ? v2_[1] : v2_[0];                                     \
        int   x_ = ib + (gf_ ? x2_[1] : x2_[0]);                              \
        {                                                                     \
            const float pv_ = __int_as_float(__builtin_amdgcn_update_dpp(     \
                0, __float_as_int(v_), 0xB1, 0xF, 0xF, true));                \
            const int   px_ = __builtin_amdgcn_update_dpp(                    \
                0, x_, 0xB1, 0xF, 0xF, true);                                 \
            const bool  pl_ = d & 1;                                          \
            const bool  tk_ = (pv_ > v_) || (pl_ && (pv_ == v_));             \
            if (tk_) { v_ = pv_; x_ = px_; }                                  \
        }                                                                     \
        {                                                                     \
            const float pv_ = __int_as_float(__builtin_amdgcn_update_dpp(     \
                0, __float_as_int(v_), 0x4E, 0xF, 0xF, true));                \
            const int   px_ = __builtin_amdgcn_update_dpp(                    \
                0, x_, 0x4E, 0xF, 0xF, true);                                 \
            const bool  pl_ = (d >> 1) & 1;                                   \
            const bool  tk_ = (pv_ > v_) || (pl_ && (pv_ == v_));             \
            if (tk_) { v_ = pv_; x_ = px_; }                                  \
        }                                                                     \
        if (d == 0) {                                                         \
            alphabuf[((T_) + 1) & 1][fj] = v_ + (PQ_);                        \
            pack |= (unsigned)x_ << (8 * (C_));                               \
            if ((C_) == 3) {                                                  \
                bp4[((size_t)(((T_) - 1) >> 2) * B_DIM + b) * C_DIM + j] =    \
                    pack;                                                     \
                pack = 0;                                                     \
            }                                                                 \
            if ((T_) + 4 < T_LEN) PQ_ = potb[((T_) + 4) * C_DIM + j];         \
        }                                                                     \
        LDS_BARRIER();                                                        \
    }

    for (int t = 1; t < 2045; t += 4) {
        STEP(t + 0, 0, pq0)
        STEP(t + 1, 1, pq1)
        STEP(t + 2, 2, pq2)
        STEP(t + 3, 3, pq3)
    }
    STEP(2045, 0, pq0)
    STEP(2046, 1, pq1)
    STEP(2047, 2, pq2)
    if (d == 0)
        bp4[((size_t)511 * B_DIM + b) * C_DIM + j] = pack;
#undef STEP
#undef ADD_TR

    if (tid < 64) {
        const float* af = alphabuf[0];
        const float v0 = af[FSKEW(tid)];
        const float v1 = af[FSKEW(tid + 64)];
        float v = v0; int x = tid;
        if (v1 > v0) { v = v1; x = tid + 64; }
#pragma unroll
        for (int mk = 1; mk < 64; mk <<= 1) {
            const float pv = __shfl_xor(v, mk);
            const int   px = __shfl_xor(x, mk);
            if (pv > v || (pv == v && px < x)) { v = pv; x = px; }
        }
        if (tid == 0) lastTag[b] = x;
    }
}

__global__ __launch_bounds__(64, 1) void viterbi_bwd(
    const unsigned* __restrict__ bp4,
    const int* __restrict__ lastTag,
    float* __restrict__ out)
{
    const int b = blockIdx.x;
    const int l = threadIdx.x;
    float* outb = out + (size_t)b * T_LEN;

    unsigned qa0 = 0, qb0 = 0, qa1 = 0, qb1 = 0,
             qa2 = 0, qb2 = 0, qa3 = 0, qb3 = 0;

    auto ld = [&](int s4, unsigned& A, unsigned& B) {
        if (s4 >= 0) {
            const unsigned* r = bp4 + ((size_t)s4 * B_DIM + b) * C_DIM;
            A = r[l];
            B = r[l + 64];
        }
    };
    ld(511, qa0, qb0);
    ld(510, qa1, qb1);
    ld(509, qa2, qb2);
    ld(508, qa3, qb3);

    int cur = lastTag[b];

    auto ext = [&](unsigned rA, unsigned rB, int c, int byte) -> int {
        const int addr = (c & 63) << 2;
        const int vA = __builtin_amdgcn_ds_bpermute(addr, (int)rA);
        const int vB = __builtin_amdgcn_ds_bpermute(addr, (int)rB);
        const int v = (c & 64) ? vB : vA;
        return (v >> (byte * 8)) & 0xFF;
    };

    {
        const unsigned rA = qa0, rB = qb0;
        const float t3 = (float)cur;
        cur = ext(rA, rB, cur, 2); const float t2 = (float)cur;
        cur = ext(rA, rB, cur, 1); const float t1 = (float)cur;
        cur = ext(rA, rB, cur, 0); const float t0 = (float)cur;
        if (l == 0) *(float4*)(outb + 4 * 511) = make_float4(t0, t1, t2, t3);
        qa0 = qa1; qb0 = qb1; qa1 = qa2; qb1 = qb2; qa2 = qa3; qb2 = qb3;
        ld(507, qa3, qb3);
    }

    for (int s4 = 510; s4 >= 0; --s4) {
        const unsigned rA = qa0, rB = qb0;
        cur = ext(rA, rB, cur, 3); const float t3 = (float)cur;
        cur = ext(rA, rB, cur, 2); const float t2 = (float)cur;
        cur = ext(rA, rB, cur, 1); const float t1 = (float)cur;
        cur = ext(rA, rB, cur, 0); const float t0 = (float)cur;
        if (l == 0) *(float4*)(outb + 4 * s4) = make_float4(t0, t1, t2, t3);
        qa0 = qa1; qb0 = qb1; qa1 = qa2; qb1 = qb2; qa2 = qa3; qb2 = qb3;
        ld(s4 - 4, qa3, qb3);
    }
}

extern "C" void kernel_launch(void* const* d_in, const int* in_sizes, int n_in,
                              void* d_out, int out_size, void* d_ws, size_t ws_size,
                              hipStream_t stream)
{
    const float* pot   = (const float*)d_in[0];   // [128, 2048, 128] f32
    const float* trans = (const float*)d_in[1];   // [128, 128] f32
    float* out = (float*)d_out;                   // [128, 2048] f32 (tags)

    const size_t vstarBytes = (size_t)B_DIM * NSTEP * C_DIM * sizeof(float); // 134,152,192

    if (ws_size >= vstarBytes + 512) {
        // V*-store forward + reduction-free backtrack
        float* vstarG = (float*)d_ws;
        int* lastTag  = (int*)((char*)d_ws + vstarBytes);
        viterbi_fwd_a<<<B_DIM, 512, 0, stream>>>(pot, trans, vstarG, lastTag);
        viterbi_bwd_v<<<B_DIM, 64, 0, stream>>>(pot, vstarG, trans, lastTag, out);
    } else {
        // FALLBACK: bp4 path (32 MiB workspace)
        unsigned* bp4 = (unsigned*)d_ws;
        int* lastTag  = (int*)((char*)d_ws + (size_t)NS4 * B_DIM * C_DIM * 4);
        viterbi_fwd<<<B_DIM, 512, 0, stream>>>(pot, trans, bp4, lastTag);
        viterbi_bwd<<<B_DIM, 64, 0, stream>>>(bp4, lastTag, out);
    }
}

// Round 5
// 1097.047 us; speedup vs baseline: 1.8027x; 1.4814x over previous
//
#include <hip/hip_runtime.h>
#include <cstdint>
#include <cstddef>

#define B_DIM 128
#define T_LEN 2048
#define C_DIM 128
#define NSTEP (T_LEN - 1)   // 2047 transition steps
#define NS4   512           // bp4-path dword-rows

// Skew: F(x) = x + 8*(x>>5). 32-float chunk c sits at 40c; the 4 chunks'
// ds_read_b128 streams hit disjoint bank quartets (verified conflict-free:
// R1 SQ_LDS_BANK_CONFLICT == 0).
#define FSKEW(x) ((x) + 8 * ((x) >> 5))

// Barrier WITHOUT vmcnt drain: cross-wave LDS visibility only needs
// lgkmcnt(0). Global loads/stores stay in flight across the barrier.
#define LDS_BARRIER() asm volatile("s_waitcnt lgkmcnt(0)\n\ts_barrier" ::: "memory")

#define TR_LIST(X) \
    X(0)  X(1)  X(2)  X(3)  X(4)  X(5)  X(6)  X(7)  \
    X(8)  X(9)  X(10) X(11) X(12) X(13) X(14) X(15) \
    X(16) X(17) X(18) X(19) X(20) X(21) X(22) X(23) \
    X(24) X(25) X(26) X(27) X(28) X(29) X(30) X(31)

template <int CTRL>
__device__ __forceinline__ float dppf(float x)
{
    return __int_as_float(__builtin_amdgcn_update_dpp(
        0, __float_as_int(x), CTRL, 0xF, 0xF, true));
}

// exact 32-way max, fuses to v_max3 chains (static indexing only)
__device__ __forceinline__ float max32(const float s[32])
{
    float u[11];
#pragma unroll
    for (int p = 0; p < 10; ++p)
        u[p] = fmaxf(fmaxf(s[3 * p], s[3 * p + 1]), s[3 * p + 2]);
    u[10] = fmaxf(s[30], s[31]);
    const float w0 = fmaxf(fmaxf(u[0], u[1]), u[2]);
    const float w1 = fmaxf(fmaxf(u[3], u[4]), u[5]);
    const float w2 = fmaxf(fmaxf(u[6], u[7]), u[8]);
    const float w3 = fmaxf(u[9], u[10]);
    return fmaxf(fmaxf(w0, w1), fmaxf(w2, w3));
}

// ===========================================================================
// Forward, value-only, FULLY BRANCHLESS inner loop.
// One block per batch, 512 threads = 8 waves (2/SIMD). Wave w owns j in
// [16w,16w+16); lane l: j = 16w + (l>>2), d = l&3, i in [32d,32d+32).
// After the 2-round DPP quad butterfly ALL 4 lanes of a quad hold the full
// 128-way max v_, so the LDS alpha write, the global V*-store and the pot
// prefetch are done by ALL lanes (same addr+value dups; LDS 4-way
// same-addr write ~free, global dups coalesce). No runtime conditionals
// => SIWaitcnt can count VMEM precisely => the 4-deep pot queue and the
// V*-stores stay in flight instead of draining each step (the R1..R4
// ~830 cyc/step latency serialization).
// ===========================================================================
__global__ __launch_bounds__(512)
__attribute__((amdgpu_waves_per_eu(2, 2)))
void viterbi_fwd_a(
    const float* __restrict__ pot,
    const float* __restrict__ trans,
    float* __restrict__ vstarG,        // [B][2047][C]: row t-1 = vstar_t
    int* __restrict__ lastTag)
{
    const int b   = blockIdx.x;
    const int tid = threadIdx.x;
    const int w   = tid >> 6;
    const int l   = tid & 63;
    const int d   = l & 3;             // i-chunk: [32d, 32d+32)
    const int j   = 16 * w + (l >> 2);
    const int fj  = FSKEW(j);
    const int ib  = 32 * d;

    __shared__ __align__(16) float alphabuf[2][160];

#define DECL_TR(K) const float tr_##K = trans[(ib + (K)) * C_DIM + j];
    TR_LIST(DECL_TR)
#undef DECL_TR

    const float* potb = pot + (size_t)b * T_LEN * C_DIM;
    float* vG = vstarG + (size_t)b * NSTEP * C_DIM;

    // alpha0 = pot[:,0] into buf[1] (step t=1 reads buf[t&1]=buf[1])
    if (tid < C_DIM) alphabuf[1][FSKEW(tid)] = potb[tid];

    // pot prefetch queue, depth 4, ALL lanes (branchless)
    float pq0 = potb[1 * C_DIM + j];
    float pq1 = potb[2 * C_DIM + j];
    float pq2 = potb[3 * C_DIM + j];
    float pq3 = potb[4 * C_DIM + j];
    __syncthreads();   // init barrier: full drain once, fine

#define ADD_TR(K) s_[K] = a_[K] + tr_##K;

#define STEP_A(T_, PQ_)                                                       \
    {                                                                         \
        const float* ac_ = &alphabuf[(T_) & 1][40 * d];                       \
        float a_[32];                                                         \
        _Pragma("unroll")                                                     \
        for (int e_ = 0; e_ < 8; ++e_)                                        \
            *(float4*)&a_[4 * e_] = *(const float4*)&ac_[4 * e_];             \
        float s_[32];                                                         \
        TR_LIST(ADD_TR)                                                       \
        float v_ = max32(s_);                                                 \
        v_ = fmaxf(v_, dppf<0xB1>(v_));                                       \
        v_ = fmaxf(v_, dppf<0x4E>(v_));                                       \
        const float av_ = v_ + (PQ_);                                         \
        alphabuf[((T_) + 1) & 1][fj] = av_;                                   \
        vG[(size_t)((T_) - 1) * C_DIM + j] = v_;                              \
        const int tn_ = ((T_) + 4 < T_LEN) ? ((T_) + 4) : (T_LEN - 1);        \
        PQ_ = potb[tn_ * C_DIM + j];   /* clamped rows never consumed */      \
        LDS_BARRIER();                                                        \
    }

    // main loop: t = 1 .. 2044 (groups of 4 for the pot-queue rotation)
    for (int t = 1; t < 2045; t += 4) {
        STEP_A(t + 0, pq0)
        STEP_A(t + 1, pq1)
        STEP_A(t + 2, pq2)
        STEP_A(t + 3, pq3)
    }
    // tail: t = 2045, 2046, 2047
    STEP_A(2045, pq0)
    STEP_A(2046, pq1)
    STEP_A(2047, pq2)
#undef STEP_A
#undef ADD_TR

    // last_tag = first-index argmax of final alpha (in buf[0]), wave 0
    if (tid < 64) {
        const float* af = alphabuf[0];
        const float v0 = af[FSKEW(tid)];
        const float v1 = af[FSKEW(tid + 64)];
        float v = v0; int x = tid;
        if (v1 > v0) { v = v1; x = tid + 64; }
#pragma unroll
        for (int mk = 1; mk < 64; mk <<= 1) {
            const float pv = __shfl_xor(v, mk);
            const int   px = __shfl_xor(x, mk);
            if (pv > v || (pv == v && px < x)) { v = pv; x = px; }
        }
        if (tid == 0) lastTag[b] = x;
    }
}

// ===========================================================================
// Reduction-free backtrack, BRANCHLESS loads. One wave per batch.
// smax = vstar_t[cur] via register readlane (no cross-lane reduce);
// argmax = equality-ballot + ffs. Loop r = 2046..1 has UNCONDITIONAL
// clamped prefetch (row max(r-6,0)) and all-lane uniform out stores, so
// the 6-deep queue pipelines (R4's guarded loads serialized at ~998
// cyc/step = HBM latency). r=0 peeled with explicit vstar_{-1} = 0.
// ===========================================================================
__global__ __launch_bounds__(64, 1) void viterbi_bwd_v(
    const float* __restrict__ pot,
    const float* __restrict__ vstarG,
    const float* __restrict__ trans,
    const int* __restrict__ lastTag,
    float* __restrict__ out)
{
    const int b = blockIdx.x;
    const int l = threadIdx.x;
    float* outb = out + (size_t)b * T_LEN;
    const float* potb = pot + (size_t)b * T_LEN * C_DIM;
    const float* vbse = vstarG + (size_t)b * NSTEP * C_DIM;

    __shared__ float Tl[C_DIM][C_DIM];   // 64 KiB, swizzled
    for (int k = l; k < C_DIM * C_DIM; k += 64) {
        const int i = k >> 7;
        const int jj = k & 127;
        Tl[i][jj ^ (i & 31)] = trans[k];
    }

    // queues over row index r, walking 2046 -> 0 (depth 6):
    // p*: pot row r ; v*: vstarG row r (= vstar_{r+1})
    float pa0, pb0, pa1, pb1, pa2, pb2, pa3, pb3, pa4, pb4, pa5, pb5;
    float va0, vb0, va1, vb1, va2, vb2, va3, vb3, va4, vb4, va5, vb5;
    auto ld = [&](int r, float& pa, float& pb, float& va, float& vb) {
        const int rr = (r > 0) ? r : 0;        // clamped, branchless
        pa = potb[(size_t)rr * C_DIM + l];
        pb = potb[(size_t)rr * C_DIM + l + 64];
        va = vbse[(size_t)rr * C_DIM + l];
        vb = vbse[(size_t)rr * C_DIM + l + 64];
    };
    ld(2046, pa0, pb0, va0, vb0);
    ld(2045, pa1, pb1, va1, vb1);
    ld(2044, pa2, pb2, va2, vb2);
    ld(2043, pa3, pb3, va3, vb3);
    ld(2042, pa4, pb4, va4, vb4);
    ld(2041, pa5, pb5, va5, vb5);

    int cur = lastTag[b];
    outb[T_LEN - 1] = (float)cur;        // uniform all-lane store
    __syncthreads();   // Tl visibility

    for (int r = NSTEP - 1; r >= 1; --r) {     // r = t-1 ; r-1 >= 0 here
        // smax = vstar_{r+1}[cur]  (row r, in registers)
        const int cl = cur & 63;
        const float rl0 = __int_as_float(
            __builtin_amdgcn_readlane(__float_as_int(va0), cl));
        const float rl1 = __int_as_float(
            __builtin_amdgcn_readlane(__float_as_int(vb0), cl));
        const float smax = (cur & 64) ? rl1 : rl0;
        // alpha_r (exact replay): pot_r + vstar_r (row r-1)
        const float a0 = pa0 + va1;
        const float a1 = pb0 + vb1;
        // T[:,cur] gather (conflict-free swizzle)
        const int sw = cur ^ (l & 31);
        const float c0 = Tl[l][sw];
        const float c1 = Tl[l + 64][sw];
        const float s0 = a0 + c0;
        const float s1 = a1 + c1;
        // exact first-index argmax: lowest i with s_i == smax
        const unsigned long long m0 = __ballot(s0 == smax);
        const unsigned long long m1 = __ballot(s1 == smax);
        cur = m0 ? (__ffsll(m0) - 1) : (64 + __ffsll(m1) - 1);
        outb[r] = (float)cur;            // uniform all-lane store
        // rotate queues, prefetch row r-6 (clamped)
        pa0 = pa1; pb0 = pb1; va0 = va1; vb0 = vb1;
        pa1 = pa2; pb1 = pb2; va1 = va2; vb1 = vb2;
        pa2 = pa3; pb2 = pb3; va2 = va3; vb2 = vb3;
        pa3 = pa4; pb3 = pb4; va3 = va4; vb3 = vb4;
        pa4 = pa5; pb4 = pb5; va4 = va5; vb4 = vb5;
        ld(r - 6, pa5, pb5, va5, vb5);
    }
    // peeled r = 0 (t = 1): vstar_{-1} = 0 -> alpha_0 = pot_0
    {
        const int cl = cur & 63;
        const float rl0 = __int_as_float(
            __builtin_amdgcn_readlane(__float_as_int(va0), cl));
        const float rl1 = __int_as_float(
            __builtin_amdgcn_readlane(__float_as_int(vb0), cl));
        const float smax = (cur & 64) ? rl1 : rl0;
        const float a0 = pa0;
        const float a1 = pb0;
        const int sw = cur ^ (l & 31);
        const float s0 = a0 + Tl[l][sw];
        const float s1 = a1 + Tl[l + 64][sw];
        const unsigned long long m0 = __ballot(s0 == smax);
        const unsigned long long m1 = __ballot(s1 == smax);
        cur = m0 ? (__ffsll(m0) - 1) : (64 + __ffsll(m1) - 1);
        outb[0] = (float)cur;
    }
}

// ===========================================================================
// FULL FALLBACK (bp4, 32 MiB workspace): verbatim verified kernels.
// ===========================================================================
__global__ __launch_bounds__(512)
__attribute__((amdgpu_waves_per_eu(2, 2)))
void viterbi_fwd(
    const float* __restrict__ pot,
    const float* __restrict__ trans,
    unsigned* __restrict__ bp4,
    int* __restrict__ lastTag)
{
    const int b   = blockIdx.x;
    const int tid = threadIdx.x;
    const int w   = tid >> 6;
    const int l   = tid & 63;
    const int d   = l & 3;
    const int j   = 16 * w + (l >> 2);
    const int fj  = FSKEW(j);
    const int ib  = 32 * d;

    __shared__ __align__(16) float alphabuf[2][160];

#define DECL_TR(K) float tr_##K = trans[(ib + (K)) * C_DIM + j];
    TR_LIST(DECL_TR)
#undef DECL_TR

    const float* potb = pot + (size_t)b * T_LEN * C_DIM;

    if (tid < C_DIM) alphabuf[1][FSKEW(tid)] = potb[tid];

    float pq0 = 0.f, pq1 = 0.f, pq2 = 0.f, pq3 = 0.f;
    if (d == 0) {
        pq0 = potb[1 * C_DIM + j];
        pq1 = potb[2 * C_DIM + j];
        pq2 = potb[3 * C_DIM + j];
        pq3 = potb[4 * C_DIM + j];
    }
    unsigned pack = 0;
    __syncthreads();

#define ADD_TR(K) s_[K] = a_[K] + tr_##K;

#define STEP(T_, C_, PQ_)                                                     \
    {                                                                         \
        const float* ac_ = &alphabuf[(T_) & 1][40 * d];                       \
        float a_[32];                                                         \
        _Pragma("unroll")                                                     \
        for (int e_ = 0; e_ < 8; ++e_)                                        \
            *(float4*)&a_[4 * e_] = *(const float4*)&ac_[4 * e_];             \
        float s_[32];                                                         \
        TR_LIST(ADD_TR)                                                       \
        float v16_[16]; int x16_[16];                                         \
        _Pragma("unroll")                                                     \
        for (int p_ = 0; p_ < 16; ++p_) {                                     \
            const bool g_ = s_[2 * p_ + 1] > s_[2 * p_];                      \
            v16_[p_] = g_ ? s_[2 * p_ + 1] : s_[2 * p_];                      \
            x16_[p_] = g_ ? 2 * p_ + 1 : 2 * p_;                              \
        }                                                                     \
        float v8_[8]; int x8_[8];                                             \
        _Pragma("unroll")                                                     \
        for (int p_ = 0; p_ < 8; ++p_) {                                      \
            const bool g_ = v16_[2 * p_ + 1] > v16_[2 * p_];                  \
            v8_[p_] = g_ ? v16_[2 * p_ + 1] : v16_[2 * p_];                   \
            x8_[p_] = g_ ? x16_[2 * p_ + 1] : x16_[2 * p_];                   \
        }                                                                     \
        float v4_[4]; int x4_[4];                                             \
        _Pragma("unroll")                                                     \
        for (int p_ = 0; p_ < 4; ++p_) {                                      \
            const bool g_ = v8_[2 * p_ + 1] > v8_[2 * p_];                    \
            v4_[p_] = g_ ? v8_[2 * p_ + 1] : v8_[2 * p_];                     \
            x4_[p_] = g_ ? x8_[2 * p_ + 1] : x8_[2 * p_];                     \
        }                                                                     \
        float v2_[2]; int x2_[2];                                             \
        _Pragma("unroll")                                                     \
        for (int p_ = 0; p_ < 2; ++p_) {                                      \
            const bool g_ = v4_[2 * p_ + 1] > v4_[2 * p_];                    \
            v2_[p_] = g_ ? v4_[2 * p_ + 1] : v4_[2 * p_];                     \
            x2_[p_] = g_ ? x4_[2 * p_ + 1] : x4_[2 * p_];                     \
        }                                                                     \
        const bool gf_ = v2_[1] > v2_[0];                                     \
        float v_ = gf_ ? v2_[1] : v2_[0];                                     \
        int   x_ = ib + (gf_ ? x2_[1] : x2_[0]);                              \
        {                                                                     \
            const float pv_ = __int_as_float(__builtin_amdgcn_update_dpp(     \
                0, __float_as_int(v_), 0xB1, 0xF, 0xF, true));                \
            const int   px_ = __builtin_amdgcn_update_dpp(                    \
                0, x_, 0xB1, 0xF, 0xF, true);                                 \
            const bool  pl_ = d & 1;                                          \
            const bool  tk_ = (pv_ > v_) || (pl_ && (pv_ == v_));             \
            if (tk_) { v_ = pv_; x_ = px_; }                                  \
        }                                                                     \
        {                                                                     \
            const float pv_ = __int_as_float(__builtin_amdgcn_update_dpp(     \
                0, __float_as_int(v_), 0x4E, 0xF, 0xF, true));                \
            const int   px_ = __builtin_amdgcn_update_dpp(                    \
                0, x_, 0x4E, 0xF, 0xF, true);                                 \
            const bool  pl_ = (d >> 1) & 1;                                   \
            const bool  tk_ = (pv_ > v_) || (pl_ && (pv_ == v_));             \
            if (tk_) { v_ = pv_; x_ = px_; }                                  \
        }                                                                     \
        if (d == 0) {                                                         \
            alphabuf[((T_) + 1) & 1][fj] = v_ + (PQ_);                        \
            pack |= (unsigned)x_ << (8 * (C_));                               \
            if ((C_) == 3) {                                                  \
                bp4[((size_t)(((T_) - 1) >> 2) * B_DIM + b) * C_DIM + j] =    \
                    pack;                                                     \
                pack = 0;                                                     \
            }                                                                 \
            if ((T_) + 4 < T_LEN) PQ_ = potb[((T_) + 4) * C_DIM + j];         \
        }                                                                     \
        LDS_BARRIER();                                                        \
    }

    for (int t = 1; t < 2045; t += 4) {
        STEP(t + 0, 0, pq0)
        STEP(t + 1, 1, pq1)
        STEP(t + 2, 2, pq2)
        STEP(t + 3, 3, pq3)
    }
    STEP(2045, 0, pq0)
    STEP(2046, 1, pq1)
    STEP(2047, 2, pq2)
    if (d == 0)
        bp4[((size_t)511 * B_DIM + b) * C_DIM + j] = pack;
#undef STEP
#undef ADD_TR

    if (tid < 64) {
        const float* af = alphabuf[0];
        const float v0 = af[FSKEW(tid)];
        const float v1 = af[FSKEW(tid + 64)];
        float v = v0; int x = tid;
        if (v1 > v0) { v = v1; x = tid + 64; }
#pragma unroll
        for (int mk = 1; mk < 64; mk <<= 1) {
            const float pv = __shfl_xor(v, mk);
            const int   px = __shfl_xor(x, mk);
            if (pv > v || (pv == v && px < x)) { v = pv; x = px; }
        }
        if (tid == 0) lastTag[b] = x;
    }
}

__global__ __launch_bounds__(64, 1) void viterbi_bwd(
    const unsigned* __restrict__ bp4,
    const int* __restrict__ lastTag,
    float* __restrict__ out)
{
    const int b = blockIdx.x;
    const int l = threadIdx.x;
    float* outb = out + (size_t)b * T_LEN;

    unsigned qa0 = 0, qb0 = 0, qa1 = 0, qb1 = 0,
             qa2 = 0, qb2 = 0, qa3 = 0, qb3 = 0;

    auto ld = [&](int s4, unsigned& A, unsigned& B) {
        if (s4 >= 0) {
            const unsigned* r = bp4 + ((size_t)s4 * B_DIM + b) * C_DIM;
            A = r[l];
            B = r[l + 64];
        }
    };
    ld(511, qa0, qb0);
    ld(510, qa1, qb1);
    ld(509, qa2, qb2);
    ld(508, qa3, qb3);

    int cur = lastTag[b];

    auto ext = [&](unsigned rA, unsigned rB, int c, int byte) -> int {
        const int addr = (c & 63) << 2;
        const int vA = __builtin_amdgcn_ds_bpermute(addr, (int)rA);
        const int vB = __builtin_amdgcn_ds_bpermute(addr, (int)rB);
        const int v = (c & 64) ? vB : vA;
        return (v >> (byte * 8)) & 0xFF;
    };

    {
        const unsigned rA = qa0, rB = qb0;
        const float t3 = (float)cur;
        cur = ext(rA, rB, cur, 2); const float t2 = (float)cur;
        cur = ext(rA, rB, cur, 1); const float t1 = (float)cur;
        cur = ext(rA, rB, cur, 0); const float t0 = (float)cur;
        if (l == 0) *(float4*)(outb + 4 * 511) = make_float4(t0, t1, t2, t3);
        qa0 = qa1; qb0 = qb1; qa1 = qa2; qb1 = qb2; qa2 = qa3; qb2 = qb3;
        ld(507, qa3, qb3);
    }

    for (int s4 = 510; s4 >= 0; --s4) {
        const unsigned rA = qa0, rB = qb0;
        cur = ext(rA, rB, cur, 3); const float t3 = (float)cur;
        cur = ext(rA, rB, cur, 2); const float t2 = (float)cur;
        cur = ext(rA, rB, cur, 1); const float t1 = (float)cur;
        cur = ext(rA, rB, cur, 0); const float t0 = (float)cur;
        if (l == 0) *(float4*)(outb + 4 * s4) = make_float4(t0, t1, t2, t3);
        qa0 = qa1; qb0 = qb1; qa1 = qa2; qb1 = qb2; qa2 = qa3; qb2 = qb3;
        ld(s4 - 4, qa3, qb3);
    }
}

extern "C" void kernel_launch(void* const* d_in, const int* in_sizes, int n_in,
                              void* d_out, int out_size, void* d_ws, size_t ws_size,
                              hipStream_t stream)
{
    const float* pot   = (const float*)d_in[0];   // [128, 2048, 128] f32
    const float* trans = (const float*)d_in[1];   // [128, 128] f32
    float* out = (float*)d_out;                   // [128, 2048] f32 (tags)

    const size_t vstarBytes = (size_t)B_DIM * NSTEP * C_DIM * sizeof(float); // 134,152,192

    if (ws_size >= vstarBytes + 512) {
        // V*-store forward + reduction-free backtrack (both branchless)
        float* vstarG = (float*)d_ws;
        int* lastTag  = (int*)((char*)d_ws + vstarBytes);
        viterbi_fwd_a<<<B_DIM, 512, 0, stream>>>(pot, trans, vstarG, lastTag);
        viterbi_bwd_v<<<B_DIM, 64, 0, stream>>>(pot, vstarG, trans, lastTag, out);
    } else {
        // FALLBACK: bp4 path (32 MiB workspace)
        unsigned* bp4 = (unsigned*)d_ws;
        int* lastTag  = (int*)((char*)d_ws + (size_t)NS4 * B_DIM * C_DIM * 4);
        viterbi_fwd<<<B_DIM, 512, 0, stream>>>(pot, trans, bp4, lastTag);
        viterbi_bwd<<<B_DIM, 64, 0, stream>>>(bp4, lastTag, out);
    }
}